// Round 5
// baseline (275.456 us; speedup 1.0000x reference)
//
#include <hip/hip_runtime.h>

// GraphSAGE 2-layer + linear head, N=50000, E=600000, C=128 everywhere.
// R4: per-layer FUSED aggregate+GEMM kernel. New agg work-split: lane
//     (quad,n15) accumulates node n15's channels [kk*32+quad*8,+8) in fp32 —
//     the mean lands directly in MFMA A-frag layout in registers (no mh
//     round-trip, no LDS transpose). Weights staged to 64KB LDS after the
//     gather loop; one barrier; v2 GEMM phase (B from LDS, self-feat V from
//     global). Evidence: R3->R4 showed launch gaps ~1us and agg insensitive
//     to issue pattern; remaining waste = inter-kernel memory round-trips.

typedef _Float16 f16;
typedef __attribute__((ext_vector_type(4))) _Float16 f16x4;
typedef __attribute__((ext_vector_type(8))) _Float16 f16x8;
typedef __attribute__((ext_vector_type(4))) float f32x4;

// ---- fused prep: [0,cb) convert x->f16 | [cb,cb+db) degree | rest: weights
// weights k-chunked transposed, 3 tables contiguous (32768 f16 each):
// wt[w][(chunk*128 + n)*8 + j] = W_w[k=chunk*8+j][n], W = [WA;WB] stacked.
__global__ void prep_kernel(const float* __restrict__ x, f16* __restrict__ xh, int n4,
                            const int* __restrict__ ei, int* __restrict__ deg, int E,
                            const float* __restrict__ W1l, const float* __restrict__ W1r,
                            const float* __restrict__ W2l, const float* __restrict__ W2r,
                            const float* __restrict__ Wlin, f16* __restrict__ wt,
                            int cb, int db) {
  int b = blockIdx.x;
  if (b < cb) {
    int i = b * 256 + threadIdx.x;
    if (i < n4) {
      const float4 v = ((const float4*)x)[i];
      f16x4 h = { (f16)v.x, (f16)v.y, (f16)v.z, (f16)v.w };
      ((f16x4*)xh)[i] = h;
    }
  } else if (b < cb + db) {
    int e = (b - cb) * 256 + threadIdx.x;
    if (e < E) atomicAdd(&deg[ei[E + e]], 1);
  } else {
    int tid = (b - cb - db) * 256 + threadIdx.x;   // 0 .. 3*32768
    int w = tid >> 15, idx = tid & 32767;
    int j = idx & 7, n = (idx >> 3) & 127, chunk = idx >> 10;
    int k = chunk * 8 + j;
    float v;
    if (w == 0) v = (k < 128) ? W1l[k * 128 + n] : W1r[(k - 128) * 128 + n];
    else if (w == 1) v = (k < 128) ? W2l[k * 128 + n] : W2r[(k - 128) * 128 + n];
    else v = Wlin[k * 128 + n];
    wt[tid] = (f16)v;
  }
}

// exclusive scan, 1024-elem chunks per block (Hillis-Steele, ping-pong LDS)
__global__ void scan_block_kernel(const int* __restrict__ in, int* __restrict__ out,
                                  int* __restrict__ sums, int n) {
  __shared__ int s[2][1024];
  int t = threadIdx.x;
  int gid = blockIdx.x * 1024 + t;
  int v = (gid < n) ? in[gid] : 0;
  int cur = 0;
  s[0][t] = v;
  __syncthreads();
  for (int ofs = 1; ofs < 1024; ofs <<= 1) {
    int nv = s[cur][t] + ((t >= ofs) ? s[cur][t - ofs] : 0);
    s[cur ^ 1][t] = nv;
    cur ^= 1;
    __syncthreads();
  }
  if (gid < n) out[gid] = s[cur][t] - v;      // exclusive within block
  if (t == 1023) sums[blockIdx.x] = s[cur][1023];
}

// adds prefix of block sums (each block redundantly reduces sums[0..b), nb<=64),
// zeroes cur[], writes off[n]=E.
__global__ void scan_add_kernel(int* __restrict__ off, const int* __restrict__ sums,
                                int* __restrict__ cur, int n, int E) {
  __shared__ int prefix_s;
  int b = blockIdx.x;
  if (threadIdx.x < 64) {
    int v = ((int)threadIdx.x < b) ? sums[threadIdx.x] : 0;
#pragma unroll
    for (int ofs = 1; ofs < 64; ofs <<= 1) v += __shfl_xor(v, ofs);
    if (threadIdx.x == 0) prefix_s = v;
  }
  __syncthreads();
  int gid = b * 1024 + threadIdx.x;
  if (gid < n) { off[gid] += prefix_s; cur[gid] = 0; }
  if (gid == 0) off[n] = E;
}

__global__ void fill_kernel(const int* __restrict__ ei, const int* __restrict__ off,
                            int* __restrict__ cursor, int* __restrict__ srcs, int E) {
  int e = blockIdx.x * blockDim.x + threadIdx.x;
  if (e < E) {
    int src = ei[e], dst = ei[E + e];
    int pos = atomicAdd(&cursor[dst], 1);
    srcs[off[dst] + pos] = src;
  }
}

// ---- fused SAGE layer: out = relu(mean_agg(feat) @ W_l + feat @ W_r + b)
// block = 256 (4 waves), 64 nodes/block (16/wave). Wave lane = (quad,n15).
// Phase 1: lane aggregates node (w*16+n15)'s channels [kk*32+quad*8,+8),
//   kk=0..3, fp32; per 2-edge round: 2 idx loads + 8 gathers in flight;
//   loop to wave-max degree (exec-masked). Mean converts to f16 A-frags.
// Stage Wt -> 64KB LDS (after gathers, hides under drain). Barrier.
// Phase 2: v2 GEMM: kk 0..3 A=mean (regs), kk 4..7 A=feat[self] (global),
//   B-frags from LDS; 8x8 MFMA; bias+relu epilogue, f16 store.
__global__ __launch_bounds__(256, 2) void sage_layer_kernel(
    const f16* __restrict__ feat, const int* __restrict__ off,
    const int* __restrict__ srcs, const f16* __restrict__ Wt,
    const float* __restrict__ bias, f16* __restrict__ outp, int M) {
  __shared__ f16 ldsw[32768];   // 64 KB
  int tid = threadIdx.x;
  int w = tid >> 6, lane = tid & 63;
  int quad = lane >> 4, n15 = lane & 15;
  int base = blockIdx.x * 64;
  int node = base + w * 16 + n15;

  int gi0 = node < M ? node : M;
  int gi1 = node + 1 < M ? node + 1 : M;
  int begL = off[gi0], endL = off[gi1];
  int degL = endL - begL;
  int maxd = degL;
#pragma unroll
  for (int ofs = 1; ofs < 64; ofs <<= 1) {
    int o = __shfl_xor(maxd, ofs);
    maxd = o > maxd ? o : maxd;
  }

  float acc[4][8] = {};
  const f16* fq = feat + quad * 8;
  int r = 0;
  for (; r + 2 <= maxd; r += 2) {
    bool a0 = r < degL, a1 = r + 1 < degL;
    int s0 = a0 ? srcs[begL + r] : 0;
    int s1 = a1 ? srcs[begL + r + 1] : 0;
    const f16* p0 = fq + (size_t)s0 * 128;
    const f16* p1 = fq + (size_t)s1 * 128;
    f16x8 g0[4], g1[4];
    if (a0) {
#pragma unroll
      for (int kk = 0; kk < 4; ++kk) g0[kk] = *(const f16x8*)(p0 + kk * 32);
    }
    if (a1) {
#pragma unroll
      for (int kk = 0; kk < 4; ++kk) g1[kk] = *(const f16x8*)(p1 + kk * 32);
    }
    if (a0) {
#pragma unroll
      for (int kk = 0; kk < 4; ++kk)
#pragma unroll
        for (int j = 0; j < 8; ++j) acc[kk][j] += (float)g0[kk][j];
    }
    if (a1) {
#pragma unroll
      for (int kk = 0; kk < 4; ++kk)
#pragma unroll
        for (int j = 0; j < 8; ++j) acc[kk][j] += (float)g1[kk][j];
    }
  }
  if (r < maxd && r < degL) {
    int s0 = srcs[begL + r];
    const f16* p0 = fq + (size_t)s0 * 128;
#pragma unroll
    for (int kk = 0; kk < 4; ++kk) {
      f16x8 g = *(const f16x8*)(p0 + kk * 32);
#pragma unroll
      for (int j = 0; j < 8; ++j) acc[kk][j] += (float)g[j];
    }
  }

  // mean -> f16 A-frags (kk 0..3)
  float inv = 1.0f / fmaxf((float)degL, 1.0f);
  f16x8 am[4];
#pragma unroll
  for (int kk = 0; kk < 4; ++kk)
#pragma unroll
    for (int j = 0; j < 8; ++j) am[kk][j] = (f16)(acc[kk][j] * inv);

  // self-feature A-frags (kk 4..7) from global
  int rowc = node < M ? node : M - 1;
  f16x8 ag[4];
  {
    const f16* ps = feat + (size_t)rowc * 128 + quad * 8;
#pragma unroll
    for (int j = 0; j < 4; ++j) ag[j] = *(const f16x8*)(ps + j * 32);
  }

  // stage Wt -> LDS (linear 64KB copy)
#pragma unroll
  for (int it = 0; it < 16; ++it) {
    int idx = it * 256 + tid;
    ((f16x8*)ldsw)[idx] = ((const f16x8*)Wt)[idx];
  }
  __syncthreads();

  f32x4 accd[8] = {};
#pragma unroll
  for (int kk = 0; kk < 8; ++kk) {
    f16x8 a = (kk < 4) ? am[kk] : ag[kk - 4];
#pragma unroll
    for (int t = 0; t < 8; ++t) {
      f16x8 b = ((const f16x8*)ldsw)[(kk * 4 + quad) * 128 + t * 16 + n15];
      accd[t] = __builtin_amdgcn_mfma_f32_16x16x32_f16(a, b, accd[t], 0, 0, 0);
    }
  }

  int rbase = base + w * 16 + quad * 4;
#pragma unroll
  for (int t = 0; t < 8; ++t) {
    float bv = bias[t * 16 + n15];
#pragma unroll
    for (int i = 0; i < 4; ++i) {
      int row = rbase + i;
      if (row < M) {
        float v = fmaxf(accd[t][i] + bv, 0.f);
        outp[(size_t)row * 128 + t * 16 + n15] = (f16)v;
      }
    }
  }
}

// head GEMM (v2): Y[M,128] = [U|V][M,256] @ W + bias, fp32 out.
template <bool RELU, bool OUT16>
__global__ __launch_bounds__(256, 2) void gemm_kernel(
    const f16* __restrict__ U, const f16* __restrict__ V, const f16* __restrict__ Wt,
    const float* __restrict__ bias, void* __restrict__ outp, int M) {
  __shared__ f16 ldsb[32768];   // 64 KB
  int tid = threadIdx.x;
  int wave = tid >> 6, lane = tid & 63;
  int quad = lane >> 4, n15 = lane & 15;
  int m0 = blockIdx.x * 128 + wave * 32;
  int kq = quad * 8;

  f16x8 a[2][8];
#pragma unroll
  for (int r = 0; r < 2; ++r) {
    int row = m0 + r * 16 + n15;
    int rowc = row < M ? row : M - 1;
    const f16* bu = U + (size_t)rowc * 128 + kq;
    const f16* bv = V + (size_t)rowc * 128 + kq;
#pragma unroll
    for (int kk = 0; kk < 4; ++kk) a[r][kk] = *(const f16x8*)(bu + kk * 32);
#pragma unroll
    for (int kk = 4; kk < 8; ++kk) a[r][kk] = *(const f16x8*)(bv + (kk - 4) * 32);
  }

#pragma unroll
  for (int it = 0; it < 16; ++it) {
    int idx = it * 256 + tid;
    ((f16x8*)ldsb)[idx] = ((const f16x8*)Wt)[idx];
  }
  __syncthreads();

  f32x4 acc[2][8] = {};
#pragma unroll
  for (int kk = 0; kk < 8; ++kk) {
#pragma unroll
    for (int t = 0; t < 8; ++t) {
      f16x8 b = ((const f16x8*)ldsb)[(kk * 4 + quad) * 128 + t * 16 + n15];
#pragma unroll
      for (int r = 0; r < 2; ++r)
        acc[r][t] = __builtin_amdgcn_mfma_f32_16x16x32_f16(a[r][kk], b, acc[r][t], 0, 0, 0);
    }
  }

  int rbase0 = m0 + quad * 4;
#pragma unroll
  for (int t = 0; t < 8; ++t) {
    float bv = bias[t * 16 + n15];
#pragma unroll
    for (int r = 0; r < 2; ++r) {
#pragma unroll
      for (int i = 0; i < 4; ++i) {
        int row = rbase0 + r * 16 + i;
        if (row < M) {
          float v = acc[r][t][i] + bv;
          if (RELU) v = fmaxf(v, 0.f);
          size_t idx = (size_t)row * 128 + t * 16 + n15;
          if (OUT16) ((f16*)outp)[idx] = (f16)v;
          else       ((float*)outp)[idx] = v;
        }
      }
    }
  }
}

extern "C" void kernel_launch(void* const* d_in, const int* in_sizes, int n_in,
                              void* d_out, int out_size, void* d_ws, size_t ws_size,
                              hipStream_t stream) {
  (void)n_in; (void)out_size; (void)ws_size;
  const float* x    = (const float*)d_in[0];
  const int*   ei   = (const int*)d_in[1];
  const float* W1l  = (const float*)d_in[2];
  const float* b1l  = (const float*)d_in[3];
  const float* W1r  = (const float*)d_in[4];
  const float* W2l  = (const float*)d_in[5];
  const float* b2l  = (const float*)d_in[6];
  const float* W2r  = (const float*)d_in[7];
  const float* Wlin = (const float*)d_in[8];
  const float* blin = (const float*)d_in[9];
  const int N = in_sizes[0] / 128;
  const int E = in_sizes[1] / 2;

  char* ws = (char*)d_ws;
  size_t o = 0;
  auto alloc = [&](size_t bytes) {
    char* p = ws + o;
    o = (o + bytes + 255) & ~(size_t)255;
    return p;
  };
  f16* xh   = (f16*)alloc((size_t)N * 128 * 2);
  f16* x1h  = (f16*)alloc((size_t)N * 128 * 2);
  f16* x2h  = (f16*)alloc((size_t)N * 128 * 2);
  f16* wt   = (f16*)alloc((size_t)3 * 32768 * 2);   // wt1|wt2|wt3 contiguous
  int* deg  = (int*)alloc((size_t)N * 4);
  int* cur  = (int*)alloc((size_t)N * 4);
  int* off  = (int*)alloc(((size_t)N + 1) * 4);
  int* srcs = (int*)alloc((size_t)E * 4);
  int* sums = (int*)alloc(64 * 4);
  f16* wt1 = wt, *wt2 = wt + 32768, *wt3 = wt + 65536;

  hipMemsetAsync(deg, 0, (size_t)N * 4, stream);

  const int n4 = N * 128 / 4;
  const int cb = (n4 + 255) / 256;           // convert blocks
  const int db = (E + 255) / 256;            // degree blocks
  const int wb = (3 * 32768) / 256;          // weight blocks
  prep_kernel<<<cb + db + wb, 256, 0, stream>>>(x, xh, n4, ei, deg, E,
                                                W1l, W1r, W2l, W2r, Wlin, wt, cb, db);

  const int nb = (N + 1023) / 1024;  // 49 for N=50000 (must be <= 64)
  scan_block_kernel<<<nb, 1024, 0, stream>>>(deg, off, sums, N);
  scan_add_kernel<<<nb, 1024, 0, stream>>>(off, sums, cur, N, E);
  fill_kernel<<<db, 256, 0, stream>>>(ei, off, cur, srcs, E);

  const int layerBlocks = (N + 63) / 64;     // 64 nodes/block
  const int gemmBlocks  = (N + 127) / 128;   // 128 rows/block

  sage_layer_kernel<<<layerBlocks, 256, 0, stream>>>(xh,  off, srcs, wt1, b1l, x1h, N);
  sage_layer_kernel<<<layerBlocks, 256, 0, stream>>>(x1h, off, srcs, wt2, b2l, x2h, N);
  gemm_kernel<false, false><<<gemmBlocks, 256, 0, stream>>>(x1h, x2h, wt3, blin, d_out, N);
}

// Round 6
// 264.759 us; speedup vs baseline: 1.0404x; 1.0404x over previous
//
#include <hip/hip_runtime.h>

// GraphSAGE 2-layer + linear head, N=50000, E=600000, C=128 everywhere.
// R5: REVERT R4 fusion (measured: 64KB-LDS kernel -> 13.9% occupancy starves
//     the gather phase; agg must run with no LDS footprint). Back to R3
//     separate agg/gemm. GEMM v3: column-split — 128 rows x 64 cols per
//     block, 32KB LDS half-stage, __launch_bounds__(256,4) => 16 waves/CU
//     (50%) vs 25%. Aggregate = R3 prefetch-all (neutral vs v2 but proven).

typedef _Float16 f16;
typedef __attribute__((ext_vector_type(4))) _Float16 f16x4;
typedef __attribute__((ext_vector_type(8))) _Float16 f16x8;
typedef __attribute__((ext_vector_type(4))) float f32x4;

// ---- fused prep: [0,cb) convert x->f16 | [cb,cb+db) degree | rest: weights
// weights k-chunked transposed, 3 tables contiguous (32768 f16 each):
// wt[w][(chunk*128 + n)*8 + j] = W_w[k=chunk*8+j][n], W = [WA;WB] stacked.
__global__ void prep_kernel(const float* __restrict__ x, f16* __restrict__ xh, int n4,
                            const int* __restrict__ ei, int* __restrict__ deg, int E,
                            const float* __restrict__ W1l, const float* __restrict__ W1r,
                            const float* __restrict__ W2l, const float* __restrict__ W2r,
                            const float* __restrict__ Wlin, f16* __restrict__ wt,
                            int cb, int db) {
  int b = blockIdx.x;
  if (b < cb) {
    int i = b * 256 + threadIdx.x;
    if (i < n4) {
      const float4 v = ((const float4*)x)[i];
      f16x4 h = { (f16)v.x, (f16)v.y, (f16)v.z, (f16)v.w };
      ((f16x4*)xh)[i] = h;
    }
  } else if (b < cb + db) {
    int e = (b - cb) * 256 + threadIdx.x;
    if (e < E) atomicAdd(&deg[ei[E + e]], 1);
  } else {
    int tid = (b - cb - db) * 256 + threadIdx.x;   // 0 .. 3*32768
    int w = tid >> 15, idx = tid & 32767;
    int j = idx & 7, n = (idx >> 3) & 127, chunk = idx >> 10;
    int k = chunk * 8 + j;
    float v;
    if (w == 0) v = (k < 128) ? W1l[k * 128 + n] : W1r[(k - 128) * 128 + n];
    else if (w == 1) v = (k < 128) ? W2l[k * 128 + n] : W2r[(k - 128) * 128 + n];
    else v = Wlin[k * 128 + n];
    wt[tid] = (f16)v;
  }
}

// exclusive scan, 1024-elem chunks per block (Hillis-Steele, ping-pong LDS)
__global__ void scan_block_kernel(const int* __restrict__ in, int* __restrict__ out,
                                  int* __restrict__ sums, int n) {
  __shared__ int s[2][1024];
  int t = threadIdx.x;
  int gid = blockIdx.x * 1024 + t;
  int v = (gid < n) ? in[gid] : 0;
  int cur = 0;
  s[0][t] = v;
  __syncthreads();
  for (int ofs = 1; ofs < 1024; ofs <<= 1) {
    int nv = s[cur][t] + ((t >= ofs) ? s[cur][t - ofs] : 0);
    s[cur ^ 1][t] = nv;
    cur ^= 1;
    __syncthreads();
  }
  if (gid < n) out[gid] = s[cur][t] - v;      // exclusive within block
  if (t == 1023) sums[blockIdx.x] = s[cur][1023];
}

// adds prefix of block sums (redundant wave-reduce, nb<=64), zeroes cur[],
// writes off[n]=E.
__global__ void scan_add_kernel(int* __restrict__ off, const int* __restrict__ sums,
                                int* __restrict__ cur, int n, int E) {
  __shared__ int prefix_s;
  int b = blockIdx.x;
  if (threadIdx.x < 64) {
    int v = ((int)threadIdx.x < b) ? sums[threadIdx.x] : 0;
#pragma unroll
    for (int ofs = 1; ofs < 64; ofs <<= 1) v += __shfl_xor(v, ofs);
    if (threadIdx.x == 0) prefix_s = v;
  }
  __syncthreads();
  int gid = b * 1024 + threadIdx.x;
  if (gid < n) { off[gid] += prefix_s; cur[gid] = 0; }
  if (gid == 0) off[n] = E;
}

__global__ void fill_kernel(const int* __restrict__ ei, const int* __restrict__ off,
                            int* __restrict__ cursor, int* __restrict__ srcs, int E) {
  int e = blockIdx.x * blockDim.x + threadIdx.x;
  if (e < E) {
    int src = ei[e], dst = ei[E + e];
    int pos = atomicAdd(&cursor[dst], 1);
    srcs[off[dst] + pos] = src;
  }
}

// agg v3 (R3): wave handles TWO nodes. lane = slot(sub) x chgroup(n15).
// Prefetch up to 24 edge indices/node, then all gathers, single drain.
#define AGG_R 6
__global__ void aggregate_kernel(const f16* __restrict__ feat, const int* __restrict__ off,
                                 const int* __restrict__ srcs, f16* __restrict__ meanf, int n) {
  int pair = (int)((blockIdx.x * blockDim.x + threadIdx.x) >> 6);
  int w0 = pair * 2;
  if (w0 >= n) return;
  int w1 = w0 + 1;
  int lane = threadIdx.x & 63;
  int sub = lane >> 4, n15 = lane & 15;
  int beg0 = off[w0], end0 = off[w0 + 1];
  int beg1 = end0;                              // CSR contiguity
  int end1 = (w1 < n) ? off[w1 + 1] : end0;
  int deg0 = end0 - beg0, deg1 = end1 - beg1;

  int s0[AGG_R], s1[AGG_R];
  bool v0[AGG_R], v1[AGG_R];
#pragma unroll
  for (int k = 0; k < AGG_R; ++k) {
    int p = 4 * k + sub;
    v0[k] = p < deg0;  s0[k] = v0[k] ? srcs[beg0 + p] : 0;
    v1[k] = p < deg1;  s1[k] = v1[k] ? srcs[beg1 + p] : 0;
  }
  f16x8 g0[AGG_R], g1[AGG_R];
#pragma unroll
  for (int k = 0; k < AGG_R; ++k) {
    if (v0[k]) g0[k] = *(const f16x8*)(feat + (size_t)s0[k] * 128 + n15 * 8);
    if (v1[k]) g1[k] = *(const f16x8*)(feat + (size_t)s1[k] * 128 + n15 * 8);
  }
  float acc0[8] = {}, acc1[8] = {};
#pragma unroll
  for (int k = 0; k < AGG_R; ++k) {
    if (v0[k]) {
#pragma unroll
      for (int j = 0; j < 8; ++j) acc0[j] += (float)g0[k][j];
    }
    if (v1[k]) {
#pragma unroll
      for (int j = 0; j < 8; ++j) acc1[j] += (float)g1[k][j];
    }
  }
  for (int e = beg0 + 4 * AGG_R; e < end0; e += 4) {   // rare deg>24 tail
    if (sub < end0 - e) {
      int s = srcs[e + sub];
      f16x8 g = *(const f16x8*)(feat + (size_t)s * 128 + n15 * 8);
#pragma unroll
      for (int j = 0; j < 8; ++j) acc0[j] += (float)g[j];
    }
  }
  for (int e = beg1 + 4 * AGG_R; e < end1; e += 4) {
    if (sub < end1 - e) {
      int s = srcs[e + sub];
      f16x8 g = *(const f16x8*)(feat + (size_t)s * 128 + n15 * 8);
#pragma unroll
      for (int j = 0; j < 8; ++j) acc1[j] += (float)g[j];
    }
  }
#pragma unroll
  for (int j = 0; j < 8; ++j) {
    acc0[j] += __shfl_xor(acc0[j], 16);
    acc0[j] += __shfl_xor(acc0[j], 32);
    acc1[j] += __shfl_xor(acc1[j], 16);
    acc1[j] += __shfl_xor(acc1[j], 32);
  }
  if (sub == 0) {
    float inv = 1.0f / fmaxf((float)deg0, 1.0f);
    f16x8 o;
#pragma unroll
    for (int j = 0; j < 8; ++j) o[j] = (f16)(acc0[j] * inv);
    *(f16x8*)(meanf + (size_t)w0 * 128 + n15 * 8) = o;
  } else if (sub == 1 && w1 < n) {
    float inv = 1.0f / fmaxf((float)deg1, 1.0f);
    f16x8 o;
#pragma unroll
    for (int j = 0; j < 8; ++j) o[j] = (f16)(acc1[j] * inv);
    *(f16x8*)(meanf + (size_t)w1 * 128 + n15 * 8) = o;
  }
}

// GEMM v3, column-split: Y[M,128] = act([U|V][M,256] @ W + bias).
// grid = 2 * ceil(M/128); bx = blockIdx.x>>1 (row block), ch = blockIdx.x&1
// (col half: cols [ch*64, ch*64+64)). Block stages its 32KB half of Wt.
// 4 waves; wave = 32 rows x 64 cols. LDS 32KB => 5 blocks/CU; lb(256,4)
// caps VGPR 128 => 16 waves/CU (50%), double the v2 occupancy.
template <bool RELU, bool OUT16>
__global__ __launch_bounds__(256, 4) void gemm_kernel(
    const f16* __restrict__ U, const f16* __restrict__ V, const f16* __restrict__ Wt,
    const float* __restrict__ bias, void* __restrict__ outp, int M) {
  __shared__ f16 ldsb[16384];   // 32 KB
  int tid = threadIdx.x;
  int wave = tid >> 6, lane = tid & 63;
  int quad = lane >> 4, n15 = lane & 15;
  int bx = blockIdx.x >> 1, ch = blockIdx.x & 1;
  int m0 = bx * 128 + wave * 32;
  int kq = quad * 8;

  // prefetch ALL A fragments (2 m-frags x 8 k-steps = 16 x 16B loads in flight)
  f16x8 a[2][8];
#pragma unroll
  for (int r = 0; r < 2; ++r) {
    int row = m0 + r * 16 + n15;
    int rowc = row < M ? row : M - 1;   // clamp tail loads (stores guarded)
    const f16* bu = U + (size_t)rowc * 128 + kq;
    const f16* bv = V + (size_t)rowc * 128 + kq;
#pragma unroll
    for (int kk = 0; kk < 4; ++kk) a[r][kk] = *(const f16x8*)(bu + kk * 32);
#pragma unroll
    for (int kk = 4; kk < 8; ++kk) a[r][kk] = *(const f16x8*)(bv + (kk - 4) * 32);
  }

  // stage our 64-col half of Wt -> LDS (2048 x 16B units, 8 iters)
  // Wt unit layout: unit = chunk*128 + n  (chunk in [0,32), n in [0,128))
  // dst  unit layout: chunk*64 + w64     (w64 = n - ch*64 in [0,64))
#pragma unroll
  for (int it = 0; it < 8; ++it) {
    int g = it * 256 + tid;
    int chunk = g >> 6, w64 = g & 63;
    ((f16x8*)ldsb)[g] = ((const f16x8*)Wt)[chunk * 128 + ch * 64 + w64];
  }
  __syncthreads();

  f32x4 acc[2][4] = {};
#pragma unroll
  for (int kk = 0; kk < 8; ++kk) {
#pragma unroll
    for (int t = 0; t < 4; ++t) {
      f16x8 b = ((const f16x8*)ldsb)[(kk * 4 + quad) * 64 + t * 16 + n15];
#pragma unroll
      for (int r = 0; r < 2; ++r)
        acc[r][t] = __builtin_amdgcn_mfma_f32_16x16x32_f16(a[r][kk], b, acc[r][t], 0, 0, 0);
    }
  }

  int rbase0 = m0 + quad * 4;
#pragma unroll
  for (int t = 0; t < 4; ++t) {
    int col = ch * 64 + t * 16 + n15;
    float bv = bias[col];
#pragma unroll
    for (int r = 0; r < 2; ++r) {
#pragma unroll
      for (int i = 0; i < 4; ++i) {
        int row = rbase0 + r * 16 + i;
        if (row < M) {
          float v = acc[r][t][i] + bv;
          if (RELU) v = fmaxf(v, 0.f);
          size_t idx = (size_t)row * 128 + col;
          if (OUT16) ((f16*)outp)[idx] = (f16)v;
          else       ((float*)outp)[idx] = v;
        }
      }
    }
  }
}

extern "C" void kernel_launch(void* const* d_in, const int* in_sizes, int n_in,
                              void* d_out, int out_size, void* d_ws, size_t ws_size,
                              hipStream_t stream) {
  (void)n_in; (void)out_size; (void)ws_size;
  const float* x    = (const float*)d_in[0];
  const int*   ei   = (const int*)d_in[1];
  const float* W1l  = (const float*)d_in[2];
  const float* b1l  = (const float*)d_in[3];
  const float* W1r  = (const float*)d_in[4];
  const float* W2l  = (const float*)d_in[5];
  const float* b2l  = (const float*)d_in[6];
  const float* W2r  = (const float*)d_in[7];
  const float* Wlin = (const float*)d_in[8];
  const float* blin = (const float*)d_in[9];
  const int N = in_sizes[0] / 128;
  const int E = in_sizes[1] / 2;

  char* ws = (char*)d_ws;
  size_t o = 0;
  auto alloc = [&](size_t bytes) {
    char* p = ws + o;
    o = (o + bytes + 255) & ~(size_t)255;
    return p;
  };
  f16* xh   = (f16*)alloc((size_t)N * 128 * 2);
  f16* x1h  = (f16*)alloc((size_t)N * 128 * 2);
  f16* x2h  = (f16*)alloc((size_t)N * 128 * 2);
  f16* mh   = (f16*)alloc((size_t)N * 128 * 2);
  f16* wt   = (f16*)alloc((size_t)3 * 32768 * 2);   // wt1|wt2|wt3 contiguous
  int* deg  = (int*)alloc((size_t)N * 4);
  int* cur  = (int*)alloc((size_t)N * 4);
  int* off  = (int*)alloc(((size_t)N + 1) * 4);
  int* srcs = (int*)alloc((size_t)E * 4);
  int* sums = (int*)alloc(64 * 4);
  f16* wt1 = wt, *wt2 = wt + 32768, *wt3 = wt + 65536;

  hipMemsetAsync(deg, 0, (size_t)N * 4, stream);

  const int n4 = N * 128 / 4;
  const int cb = (n4 + 255) / 256;           // convert blocks
  const int db = (E + 255) / 256;            // degree blocks
  const int wb = (3 * 32768) / 256;          // weight blocks
  prep_kernel<<<cb + db + wb, 256, 0, stream>>>(x, xh, n4, ei, deg, E,
                                                W1l, W1r, W2l, W2r, Wlin, wt, cb, db);

  const int nb = (N + 1023) / 1024;  // 49 for N=50000 (must be <= 64)
  scan_block_kernel<<<nb, 1024, 0, stream>>>(deg, off, sums, N);
  scan_add_kernel<<<nb, 1024, 0, stream>>>(off, sums, cur, N, E);
  fill_kernel<<<db, 256, 0, stream>>>(ei, off, cur, srcs, E);

  const int aggBlocks  = ((N + 1) / 2 + 3) / 4;   // 2 nodes/wave, 4 waves/block
  const int gemmBlocks = 2 * ((N + 127) / 128);   // col-split x2

  // layer 1: x1 = relu(mean(x) @ W1_l + x @ W1_r + b1)
  aggregate_kernel<<<aggBlocks, 256, 0, stream>>>(xh, off, srcs, mh, N);
  gemm_kernel<true, true><<<gemmBlocks, 256, 0, stream>>>(mh, xh, wt1, b1l, x1h, N);
  // layer 2: x2 = relu(mean(x1) @ W2_l + x1 @ W2_r + b2)
  aggregate_kernel<<<aggBlocks, 256, 0, stream>>>(x1h, off, srcs, mh, N);
  gemm_kernel<true, true><<<gemmBlocks, 256, 0, stream>>>(mh, x1h, wt2, b2l, x2h, N);
  // head: out = [x1|x2] @ W_lin + b_lin   (fp32 out)
  gemm_kernel<false, false><<<gemmBlocks, 256, 0, stream>>>(x1h, x2h, wt3, blin, d_out, N);
}

// Round 7
// 229.005 us; speedup vs baseline: 1.2028x; 1.1561x over previous
//
#include <hip/hip_runtime.h>

// GraphSAGE 2-layer + linear head, N=50000, E=600000, C=128 everywhere.
// R6: CSR build rebuilt ATOMIC-FREE (two-level bucket sort by dst):
//     hist(dst>>8) -> hierarchical scan of 256xNB table -> deterministic
//     per-(block,bin) scatter of (dst,src) pairs -> per-bucket LDS sort
//     emitting off[] and srcs[] directly. Removes both 600k device-scope
//     atomic passes (deg count + fill) + memset + deg/cur arrays.
//     Ledger evidence: agg+gemm ~= 111us measured; ~150us hides in the
//     CSR/prep chain => cross-XCD fabric atomics are the prime suspect.

typedef _Float16 f16;
typedef __attribute__((ext_vector_type(4))) _Float16 f16x4;
typedef __attribute__((ext_vector_type(8))) _Float16 f16x8;
typedef __attribute__((ext_vector_type(4))) float f32x4;

#define RNB 128   // radix pass-1 blocks (256 bins x 128 = 32768 scan entries)

// ---- fused prep: [0,cb) convert x->f16 | rest: weight transpose
// weights k-chunked transposed, 3 tables contiguous (32768 f16 each):
// wt[w][(chunk*128 + n)*8 + j] = W_w[k=chunk*8+j][n], W = [WA;WB] stacked.
__global__ void prep_kernel(const float* __restrict__ x, f16* __restrict__ xh, int n4,
                            const float* __restrict__ W1l, const float* __restrict__ W1r,
                            const float* __restrict__ W2l, const float* __restrict__ W2r,
                            const float* __restrict__ Wlin, f16* __restrict__ wt,
                            int cb) {
  int b = blockIdx.x;
  if (b < cb) {
    int i = b * 256 + threadIdx.x;
    if (i < n4) {
      const float4 v = ((const float4*)x)[i];
      f16x4 h = { (f16)v.x, (f16)v.y, (f16)v.z, (f16)v.w };
      ((f16x4*)xh)[i] = h;
    }
  } else {
    int tid = (b - cb) * 256 + threadIdx.x;   // 0 .. 3*32768
    int w = tid >> 15, idx = tid & 32767;
    int j = idx & 7, n = (idx >> 3) & 127, chunk = idx >> 10;
    int k = chunk * 8 + j;
    float v;
    if (w == 0) v = (k < 128) ? W1l[k * 128 + n] : W1r[(k - 128) * 128 + n];
    else if (w == 1) v = (k < 128) ? W2l[k * 128 + n] : W2r[(k - 128) * 128 + n];
    else v = Wlin[k * 128 + n];
    wt[tid] = (f16)v;
  }
}

// pass A: per-block 256-bin LDS histogram of dst>>8; ghist[bin*RNB + b].
__global__ void radix_hist(const int* __restrict__ ei, int* __restrict__ ghist, int E) {
  __shared__ int h[256];
  int tid = threadIdx.x, b = blockIdx.x;
  h[tid] = 0;
  __syncthreads();
  int per = (E + RNB - 1) / RNB;
  int s = b * per, e = s + per; if (e > E) e = E;
  for (int i = s + tid; i < e; i += 256) atomicAdd(&h[ei[E + i] >> 8], 1);
  __syncthreads();
  ghist[tid * RNB + b] = h[tid];
}

// exclusive scan, 1024-elem chunks per block (Hillis-Steele, ping-pong LDS)
__global__ void scan_block_kernel(const int* __restrict__ in, int* __restrict__ out,
                                  int* __restrict__ sums, int n) {
  __shared__ int s[2][1024];
  int t = threadIdx.x;
  int gid = blockIdx.x * 1024 + t;
  int v = (gid < n) ? in[gid] : 0;
  int cur = 0;
  s[0][t] = v;
  __syncthreads();
  for (int ofs = 1; ofs < 1024; ofs <<= 1) {
    int nv = s[cur][t] + ((t >= ofs) ? s[cur][t - ofs] : 0);
    s[cur ^ 1][t] = nv;
    cur ^= 1;
    __syncthreads();
  }
  if (gid < n) out[gid] = s[cur][t] - v;      // exclusive within block
  if (t == 1023) sums[blockIdx.x] = s[cur][1023];
}

// adds prefix of block sums (redundant wave-reduce per block, nb<=64)
__global__ void scan_add_kernel(int* __restrict__ data, const int* __restrict__ sums, int n) {
  __shared__ int prefix_s;
  int b = blockIdx.x;
  if (threadIdx.x < 64) {
    int v = ((int)threadIdx.x < b) ? sums[threadIdx.x] : 0;
#pragma unroll
    for (int ofs = 1; ofs < 64; ofs <<= 1) v += __shfl_xor(v, ofs);
    if (threadIdx.x == 0) prefix_s = v;
  }
  __syncthreads();
  int gid = b * 1024 + threadIdx.x;
  if (gid < n) data[gid] += prefix_s;
}

// pass C: deterministic scatter into per-(block,bin) ranges; LDS cursors only.
__global__ void radix_scatter(const int* __restrict__ ei, const int* __restrict__ sg,
                              int2* __restrict__ tmp, int E) {
  __shared__ int cur[256];
  int tid = threadIdx.x, b = blockIdx.x;
  cur[tid] = sg[tid * RNB + b];
  __syncthreads();
  int per = (E + RNB - 1) / RNB;
  int s = b * per, e = s + per; if (e > E) e = E;
  for (int i = s + tid; i < e; i += 256) {
    int d = ei[E + i], sr = ei[i];
    int pos = atomicAdd(&cur[d >> 8], 1);     // LDS atomic
    tmp[pos] = make_int2(d, sr);
  }
}

// pass D: one block per high-byte bucket. LDS low-byte hist + scan ->
// emits off[] for its 256 dst values and scatters srcs (L2-local window).
__global__ void radix_bucket(const int2* __restrict__ tmp, const int* __restrict__ sg,
                             int* __restrict__ srcs, int* __restrict__ off,
                             int N, int E, int HB) {
  __shared__ int h[256], sc[256], cur[256];
  int tid = threadIdx.x, hb = blockIdx.x;
  int start = sg[hb * RNB];
  int end = (hb + 1 < HB) ? sg[(hb + 1) * RNB] : E;
  h[tid] = 0;
  __syncthreads();
  for (int i = start + tid; i < end; i += 256) atomicAdd(&h[tmp[i].x & 255], 1);
  __syncthreads();
  sc[tid] = h[tid];
  __syncthreads();
  for (int o = 1; o < 256; o <<= 1) {
    int u = (tid >= o) ? sc[tid - o] : 0;
    __syncthreads();
    sc[tid] += u;
    __syncthreads();
  }
  int excl = sc[tid] - h[tid];
  int v = (hb << 8) + tid;
  if (v < N) off[v] = start + excl;
  if (hb == 0 && tid == 0) off[N] = E;
  cur[tid] = start + excl;
  __syncthreads();
  for (int i = start + tid; i < end; i += 256) {
    int2 p = tmp[i];
    int pos = atomicAdd(&cur[p.x & 255], 1);  // LDS atomic
    srcs[pos] = p.y;
  }
}

// agg v3 (R3): wave handles TWO nodes. lane = slot(sub) x chgroup(n15).
// Prefetch up to 24 edge indices/node, then all gathers, single drain.
#define AGG_R 6
__global__ void aggregate_kernel(const f16* __restrict__ feat, const int* __restrict__ off,
                                 const int* __restrict__ srcs, f16* __restrict__ meanf, int n) {
  int pair = (int)((blockIdx.x * blockDim.x + threadIdx.x) >> 6);
  int w0 = pair * 2;
  if (w0 >= n) return;
  int w1 = w0 + 1;
  int lane = threadIdx.x & 63;
  int sub = lane >> 4, n15 = lane & 15;
  int beg0 = off[w0], end0 = off[w0 + 1];
  int beg1 = end0;                              // CSR contiguity
  int end1 = (w1 < n) ? off[w1 + 1] : end0;
  int deg0 = end0 - beg0, deg1 = end1 - beg1;

  int s0[AGG_R], s1[AGG_R];
  bool v0[AGG_R], v1[AGG_R];
#pragma unroll
  for (int k = 0; k < AGG_R; ++k) {
    int p = 4 * k + sub;
    v0[k] = p < deg0;  s0[k] = v0[k] ? srcs[beg0 + p] : 0;
    v1[k] = p < deg1;  s1[k] = v1[k] ? srcs[beg1 + p] : 0;
  }
  f16x8 g0[AGG_R], g1[AGG_R];
#pragma unroll
  for (int k = 0; k < AGG_R; ++k) {
    if (v0[k]) g0[k] = *(const f16x8*)(feat + (size_t)s0[k] * 128 + n15 * 8);
    if (v1[k]) g1[k] = *(const f16x8*)(feat + (size_t)s1[k] * 128 + n15 * 8);
  }
  float acc0[8] = {}, acc1[8] = {};
#pragma unroll
  for (int k = 0; k < AGG_R; ++k) {
    if (v0[k]) {
#pragma unroll
      for (int j = 0; j < 8; ++j) acc0[j] += (float)g0[k][j];
    }
    if (v1[k]) {
#pragma unroll
      for (int j = 0; j < 8; ++j) acc1[j] += (float)g1[k][j];
    }
  }
  for (int e = beg0 + 4 * AGG_R; e < end0; e += 4) {   // rare deg>24 tail
    if (sub < end0 - e) {
      int s = srcs[e + sub];
      f16x8 g = *(const f16x8*)(feat + (size_t)s * 128 + n15 * 8);
#pragma unroll
      for (int j = 0; j < 8; ++j) acc0[j] += (float)g[j];
    }
  }
  for (int e = beg1 + 4 * AGG_R; e < end1; e += 4) {
    if (sub < end1 - e) {
      int s = srcs[e + sub];
      f16x8 g = *(const f16x8*)(feat + (size_t)s * 128 + n15 * 8);
#pragma unroll
      for (int j = 0; j < 8; ++j) acc1[j] += (float)g[j];
    }
  }
#pragma unroll
  for (int j = 0; j < 8; ++j) {
    acc0[j] += __shfl_xor(acc0[j], 16);
    acc0[j] += __shfl_xor(acc0[j], 32);
    acc1[j] += __shfl_xor(acc1[j], 16);
    acc1[j] += __shfl_xor(acc1[j], 32);
  }
  if (sub == 0) {
    float inv = 1.0f / fmaxf((float)deg0, 1.0f);
    f16x8 o;
#pragma unroll
    for (int j = 0; j < 8; ++j) o[j] = (f16)(acc0[j] * inv);
    *(f16x8*)(meanf + (size_t)w0 * 128 + n15 * 8) = o;
  } else if (sub == 1 && w1 < n) {
    float inv = 1.0f / fmaxf((float)deg1, 1.0f);
    f16x8 o;
#pragma unroll
    for (int j = 0; j < 8; ++j) o[j] = (f16)(acc1[j] * inv);
    *(f16x8*)(meanf + (size_t)w1 * 128 + n15 * 8) = o;
  }
}

// GEMM v3, column-split: Y[M,128] = act([U|V][M,256] @ W + bias).
// grid = 2 * ceil(M/128); 32KB LDS half-stage, lb(256,4) => 16 waves/CU.
template <bool RELU, bool OUT16>
__global__ __launch_bounds__(256, 4) void gemm_kernel(
    const f16* __restrict__ U, const f16* __restrict__ V, const f16* __restrict__ Wt,
    const float* __restrict__ bias, void* __restrict__ outp, int M) {
  __shared__ f16 ldsb[16384];   // 32 KB
  int tid = threadIdx.x;
  int wave = tid >> 6, lane = tid & 63;
  int quad = lane >> 4, n15 = lane & 15;
  int bx = blockIdx.x >> 1, ch = blockIdx.x & 1;
  int m0 = bx * 128 + wave * 32;
  int kq = quad * 8;

  f16x8 a[2][8];
#pragma unroll
  for (int r = 0; r < 2; ++r) {
    int row = m0 + r * 16 + n15;
    int rowc = row < M ? row : M - 1;   // clamp tail loads (stores guarded)
    const f16* bu = U + (size_t)rowc * 128 + kq;
    const f16* bv = V + (size_t)rowc * 128 + kq;
#pragma unroll
    for (int kk = 0; kk < 4; ++kk) a[r][kk] = *(const f16x8*)(bu + kk * 32);
#pragma unroll
    for (int kk = 4; kk < 8; ++kk) a[r][kk] = *(const f16x8*)(bv + (kk - 4) * 32);
  }

#pragma unroll
  for (int it = 0; it < 8; ++it) {
    int g = it * 256 + tid;
    int chunk = g >> 6, w64 = g & 63;
    ((f16x8*)ldsb)[g] = ((const f16x8*)Wt)[chunk * 128 + ch * 64 + w64];
  }
  __syncthreads();

  f32x4 acc[2][4] = {};
#pragma unroll
  for (int kk = 0; kk < 8; ++kk) {
#pragma unroll
    for (int t = 0; t < 4; ++t) {
      f16x8 b = ((const f16x8*)ldsb)[(kk * 4 + quad) * 64 + t * 16 + n15];
#pragma unroll
      for (int r = 0; r < 2; ++r)
        acc[r][t] = __builtin_amdgcn_mfma_f32_16x16x32_f16(a[r][kk], b, acc[r][t], 0, 0, 0);
    }
  }

  int rbase0 = m0 + quad * 4;
#pragma unroll
  for (int t = 0; t < 4; ++t) {
    int col = ch * 64 + t * 16 + n15;
    float bv = bias[col];
#pragma unroll
    for (int r = 0; r < 2; ++r) {
#pragma unroll
      for (int i = 0; i < 4; ++i) {
        int row = rbase0 + r * 16 + i;
        if (row < M) {
          float v = acc[r][t][i] + bv;
          if (RELU) v = fmaxf(v, 0.f);
          size_t idx = (size_t)row * 128 + col;
          if (OUT16) ((f16*)outp)[idx] = (f16)v;
          else       ((float*)outp)[idx] = v;
        }
      }
    }
  }
}

extern "C" void kernel_launch(void* const* d_in, const int* in_sizes, int n_in,
                              void* d_out, int out_size, void* d_ws, size_t ws_size,
                              hipStream_t stream) {
  (void)n_in; (void)out_size; (void)ws_size;
  const float* x    = (const float*)d_in[0];
  const int*   ei   = (const int*)d_in[1];
  const float* W1l  = (const float*)d_in[2];
  const float* b1l  = (const float*)d_in[3];
  const float* W1r  = (const float*)d_in[4];
  const float* W2l  = (const float*)d_in[5];
  const float* b2l  = (const float*)d_in[6];
  const float* W2r  = (const float*)d_in[7];
  const float* Wlin = (const float*)d_in[8];
  const float* blin = (const float*)d_in[9];
  const int N = in_sizes[0] / 128;
  const int E = in_sizes[1] / 2;

  char* ws = (char*)d_ws;
  size_t o = 0;
  auto alloc = [&](size_t bytes) {
    char* p = ws + o;
    o = (o + bytes + 255) & ~(size_t)255;
    return p;
  };
  f16*  xh   = (f16*)alloc((size_t)N * 128 * 2);
  f16*  x1h  = (f16*)alloc((size_t)N * 128 * 2);
  f16*  x2h  = (f16*)alloc((size_t)N * 128 * 2);
  f16*  mh   = (f16*)alloc((size_t)N * 128 * 2);
  f16*  wt   = (f16*)alloc((size_t)3 * 32768 * 2);   // wt1|wt2|wt3 contiguous
  int*  off  = (int*)alloc(((size_t)N + 1) * 4);
  int*  srcs = (int*)alloc((size_t)E * 4);
  int2* tmp  = (int2*)alloc((size_t)E * 8);
  int*  ghist= (int*)alloc(256 * RNB * 4);
  int*  sg   = (int*)alloc(256 * RNB * 4);
  int*  sums = (int*)alloc(64 * 4);
  f16* wt1 = wt, *wt2 = wt + 32768, *wt3 = wt + 65536;

  const int n4 = N * 128 / 4;
  const int cb = (n4 + 255) / 256;           // convert blocks
  const int wb = (3 * 32768) / 256;          // weight blocks
  const int HB = (N + 255) / 256;            // high-byte buckets (196)
  const int SN = 256 * RNB;                  // scan length 32768
  const int snb = SN / 1024;                 // 32 scan blocks (<=64)

  // CSR build (atomic-free)
  radix_hist<<<RNB, 256, 0, stream>>>(ei, ghist, E);
  scan_block_kernel<<<snb, 1024, 0, stream>>>(ghist, sg, sums, SN);
  scan_add_kernel<<<snb, 1024, 0, stream>>>(sg, sums, SN);
  radix_scatter<<<RNB, 256, 0, stream>>>(ei, sg, tmp, E);
  radix_bucket<<<HB, 256, 0, stream>>>(tmp, sg, srcs, off, N, E, HB);

  // feature convert + weight transpose
  prep_kernel<<<cb + wb, 256, 0, stream>>>(x, xh, n4, W1l, W1r, W2l, W2r, Wlin, wt, cb);

  const int aggBlocks  = ((N + 1) / 2 + 3) / 4;   // 2 nodes/wave, 4 waves/block
  const int gemmBlocks = 2 * ((N + 127) / 128);   // col-split x2

  // layer 1: x1 = relu(mean(x) @ W1_l + x @ W1_r + b1)
  aggregate_kernel<<<aggBlocks, 256, 0, stream>>>(xh, off, srcs, mh, N);
  gemm_kernel<true, true><<<gemmBlocks, 256, 0, stream>>>(mh, xh, wt1, b1l, x1h, N);
  // layer 2: x2 = relu(mean(x1) @ W2_l + x1 @ W2_r + b2)
  aggregate_kernel<<<aggBlocks, 256, 0, stream>>>(x1h, off, srcs, mh, N);
  gemm_kernel<true, true><<<gemmBlocks, 256, 0, stream>>>(mh, x1h, wt2, b2l, x2h, N);
  // head: out = [x1|x2] @ W_lin + b_lin   (fp32 out)
  gemm_kernel<false, false><<<gemmBlocks, 256, 0, stream>>>(x1h, x2h, wt3, blin, d_out, N);
}